// Round 2
// baseline (25225.317 us; speedup 1.0000x reference)
//
#include <hip/hip_runtime.h>

constexpr int kB   = 32;    // batch
constexpr int kNS  = 100;   // n_support
constexpr int kNW  = 10;    // n_way
constexpr int kNZ  = 1000;  // kNS*kNW
constexpr int kD   = 512;   // feature dim
constexpr int kNQ  = 150;   // N*Q query rows
constexpr int kIt  = 15;    // IPM iterations
constexpr int kHalf = 50;   // rows per register strip

// -------------------------------------------------------------------------
// K[b][i][j] = <sup_i, sup_j>  (fp32 accumulate, stored fp64 for the IPM)
__global__ __launch_bounds__(128) void gram_kernel(const float* __restrict__ sup,
                                                   double* __restrict__ K64)
{
    const int i = blockIdx.x;
    const int b = blockIdx.y;
    const int tid = threadIdx.x;
    __shared__ float rowi[kD];
    const float* supb = sup + (size_t)b * kNS * kD;
    reinterpret_cast<float4*>(rowi)[tid] =
        reinterpret_cast<const float4*>(supb + (size_t)i * kD)[tid];
    __syncthreads();
    for (int j = tid; j < kNS; j += 128) {
        const float4* rj = reinterpret_cast<const float4*>(supb + (size_t)j * kD);
        float acc = 0.0f;
        for (int d4 = 0; d4 < kD / 4; ++d4) {
            float4 v = rj[d4];
            acc += rowi[4*d4+0]*v.x + rowi[4*d4+1]*v.y
                 + rowi[4*d4+2]*v.z + rowi[4*d4+3]*v.w;
        }
        K64[((size_t)b * kNS + i) * kNS + j] = (double)acc;
    }
}

// compat[b][i][q] = <sup_i, qry_q>
__global__ __launch_bounds__(256) void compat_kernel(const float* __restrict__ sup,
                                                     const float* __restrict__ qry,
                                                     float* __restrict__ compat)
{
    const int i = blockIdx.x;
    const int b = blockIdx.y;
    const int tid = threadIdx.x;
    __shared__ float rowi[kD];
    const float* supb = sup + (size_t)b * kNS * kD;
    const float* qryb = qry + (size_t)b * kNQ * kD;
    if (tid < 128)
        reinterpret_cast<float4*>(rowi)[tid] =
            reinterpret_cast<const float4*>(supb + (size_t)i * kD)[tid];
    __syncthreads();
    for (int j = tid; j < kNQ; j += 256) {
        const float4* rj = reinterpret_cast<const float4*>(qryb + (size_t)j * kD);
        float acc = 0.0f;
        for (int d4 = 0; d4 < kD / 4; ++d4) {
            float4 v = rj[d4];
            acc += rowi[4*d4+0]*v.x + rowi[4*d4+1]*v.y
                 + rowi[4*d4+2]*v.z + rowi[4*d4+3]*v.w;
        }
        compat[((size_t)b * kNS + i) * kNQ + j] = acc;
    }
}

__global__ __launch_bounds__(256) void init_kernel(double* __restrict__ z,
                                                   double* __restrict__ nu,
                                                   double* __restrict__ s,
                                                   double* __restrict__ lam,
                                                   double* __restrict__ mu_g)
{
    const int b = blockIdx.x;
    const int tid = threadIdx.x;
    for (int m = tid; m < kNZ; m += 256) {
        z[b*kNZ + m]   = 0.0;
        s[b*kNZ + m]   = 1.0;
        lam[b*kNZ + m] = 1.0;
    }
    if (tid < kNS) nu[b*kNS + tid] = 0.0;
    if (tid == 0)  mu_g[b] = 1.0;   // dot(s0,lam0)/kNZ
}

// -------------------------------------------------------------------------
// One block per (b,a). Register-resident Gauss-Jordan inverse of
// H_a = K + diag(1 + lam_a/s_a). Thread (h=tid>>7, j=tid&127) owns rows
// [h*50, h*50+50) of column j. Symmetric-GJ invariant: H[i][k] = -H[k][i]
// for processed i (<k), +H[k][i] for unprocessed -> only row k is shared.
__global__ __launch_bounds__(256) void ipm_invert_kernel(
    const double* __restrict__ K64, const int* __restrict__ labels,
    const double* __restrict__ z, const double* __restrict__ nu,
    const double* __restrict__ s, const double* __restrict__ lam,
    const double* __restrict__ mu_g,
    double* __restrict__ Hinv, double* __restrict__ tvec,
    double* __restrict__ r1g)
{
    const int b = blockIdx.x / kNW;
    const int a = blockIdx.x - b * kNW;
    const int tid = threadIdx.x;
    const int h = tid >> 7;
    const int j = tid & 127;
    const bool act = (j < kNS);
    const int base = h * kHalf;

    __shared__ double za[kNS], sa[kNS], la[kNS], da[kNS], nus[kNS], r1s[kNS];
    __shared__ double part2[2][kNS];
    __shared__ double rowk[2][kNS + 4];
    __shared__ int    labs[kNS];

    const double* zb = z   + (size_t)b * kNZ;
    const double* sb = s   + (size_t)b * kNZ;
    const double* lb = lam + (size_t)b * kNZ;
    const double* Kb = K64 + (size_t)b * kNS * kNS;

    if (tid < kNS) {
        double zv = zb[tid * kNW + a];
        double sv = sb[tid * kNW + a];
        double lv = lb[tid * kNW + a];
        za[tid] = zv; sa[tid] = sv; la[tid] = lv; da[tid] = lv / sv;
        nus[tid]  = nu[b * kNS + tid];
        labs[tid] = labels[b * kNS + tid];
    }
    __syncthreads();

    // Build H column j in registers; fused partial of (K z_a) via symmetry.
    double hreg[kHalf];
    if (act) {
        double kzp = 0.0;
        #pragma unroll
        for (int r = 0; r < kHalf; ++r) {
            const int i = base + r;
            double kv = Kb[(size_t)i * kNS + j];
            kzp += kv * za[i];
            hreg[r] = (i == j) ? (kv + 1.0 + da[j]) : kv;
        }
        part2[h][j] = kzp;
    }
    __syncthreads();
    if (tid < kNS) {
        const double mu = mu_g[b];
        const int i = tid;
        double kz = part2[0][i] + part2[1][i];
        double yv = (labs[i] == a) ? 1.0 : 0.0;
        double rd = kz + za[i] - yv + la[i] + nus[i];
        double rp = za[i] + sa[i] - 0.1 * yv;      // h = C_REG*y
        double rc = la[i] * sa[i] - 0.1 * mu;      // sigma = 0.1
        double v = -rd + (rc - la[i] * rp) / sa[i];
        r1s[i] = v;
        r1g[(size_t)(b * kNW + a) * kNS + i] = v;
    }
    __syncthreads();

    // Gauss-Jordan in-place inverse, 1 barrier per pivot (double-buffered rowk)
    #pragma unroll 1
    for (int k = 0; k < kNS; ++k) {
        const int buf = k & 1;
        const int kh = (k >= kHalf) ? 1 : 0;
        if (act && h == kh) rowk[buf][j] = hreg[k - kh * kHalf];
        __syncthreads();
        if (act) {
            const double pivinv = 1.0 / rowk[buf][k];
            const bool jk = (j == k);
            const double nrkj = (jk ? 1.0 : rowk[buf][j]) * pivinv;
            #pragma unroll
            for (int r = 0; r < kHalf; ++r) {
                const int i = base + r;
                double rv = rowk[buf][i];           // broadcast read
                double ci = (i < k) ? -rv : rv;     // symmetric-GJ invariant
                double he = jk ? 0.0 : hreg[r];
                double hn = he - ci * nrkj;
                hreg[r] = (i == k) ? nrkj : hn;
            }
        }
    }

    // Write Hinv (coalesced) + t_a = Hinv * r1 (2-way combine via symmetry)
    double* Hb = Hinv + (size_t)(b * kNW + a) * kNS * kNS;
    if (act) {
        double tp = 0.0;
        #pragma unroll
        for (int r = 0; r < kHalf; ++r) {
            Hb[(size_t)(base + r) * kNS + j] = hreg[r];
            tp += hreg[r] * r1s[base + r];
        }
        part2[h][j] = tp;
    }
    __syncthreads();
    if (tid < kNS)
        tvec[(size_t)(b * kNW + a) * kNS + tid] = part2[0][tid] + part2[1][tid];
}

// -------------------------------------------------------------------------
// One block per b: S = sum_a Hinv_a (registers), GJ solve [S | rhs],
// dz_a = Hinv_a (r1_a - dnu) via coalesced streaming + symmetry,
// min-ratio step, state update, next-iteration mu.
__global__ __launch_bounds__(256) void ipm_schur_kernel(
    const int* __restrict__ labels,
    const double* __restrict__ Hinv, const double* __restrict__ tvec,
    const double* __restrict__ r1g,
    double* __restrict__ z, double* __restrict__ nu,
    double* __restrict__ s, double* __restrict__ lam,
    double* __restrict__ mu_g)
{
    const int b = blockIdx.x;
    const int tid = threadIdx.x;
    const int h = tid >> 7;
    const int j = tid & 127;
    const int base = h * kHalf;
    const bool act  = (j < kNS);     // matrix columns
    const bool actS = (j <= kNS);    // + rhs column (j == 100)

    __shared__ double vall[kNW][kNS];     // r1_a, then v_a = r1_a - dnu
    __shared__ double rhs[kNS];
    __shared__ double dnu_s[kNS];
    __shared__ double rowk[2][kNS + 8];
    __shared__ double tp2[kNW][2][kNS];
    __shared__ double dzv[kNZ];
    __shared__ double red[256];

    double* zb  = z   + (size_t)b * kNZ;
    double* sb  = s   + (size_t)b * kNZ;
    double* lb  = lam + (size_t)b * kNZ;
    double* nub = nu  + (size_t)b * kNS;
    const double* Hb  = Hinv + (size_t)b * kNW * kNS * kNS;
    const double* tb  = tvec + (size_t)b * kNW * kNS;
    const double* r1b = r1g  + (size_t)b * kNW * kNS;
    const int* labb = labels + b * kNS;
    const double mu = mu_g[b];

    for (int m = tid; m < kNZ; m += 256) {
        int aa = m / kNS, ii = m - aa * kNS;
        vall[aa][ii] = r1b[m];
    }
    if (tid < kNS) {
        double acc = 0.0, rp2 = 0.0;
        #pragma unroll
        for (int a = 0; a < kNW; ++a) {
            acc += tb[a * kNS + tid];
            rp2 += zb[tid * kNW + a];
        }
        rhs[tid] = acc + rp2;
    }
    __syncthreads();

    // S columns in registers (coalesced streaming read of Hinv)
    double sreg[kHalf];
    if (act) {
        #pragma unroll
        for (int r = 0; r < kHalf; ++r) {
            double acc = 0.0;
            #pragma unroll
            for (int a = 0; a < kNW; ++a)
                acc += Hb[(size_t)a * kNS * kNS + (size_t)(base + r) * kNS + j];
            sreg[r] = acc;
        }
    } else if (j == kNS) {
        #pragma unroll
        for (int r = 0; r < kHalf; ++r) sreg[r] = rhs[base + r];
    }

    // GJ (inverse-style recurrence so the symmetry invariant holds); the
    // rhs column (j==100, never ==k) receives pure row ops -> solution.
    #pragma unroll 1
    for (int k = 0; k < kNS; ++k) {
        const int buf = k & 1;
        const int kh = (k >= kHalf) ? 1 : 0;
        if (actS && h == kh) rowk[buf][j] = sreg[k - kh * kHalf];
        __syncthreads();
        if (actS) {
            const double pivinv = 1.0 / rowk[buf][k];
            const bool jk = (j == k);
            const double nrkj = (jk ? 1.0 : rowk[buf][j]) * pivinv;
            #pragma unroll
            for (int r = 0; r < kHalf; ++r) {
                const int i = base + r;
                double rv = rowk[buf][i];
                double ci = (i < k) ? -rv : rv;
                double he = jk ? 0.0 : sreg[r];
                double hn = he - ci * nrkj;
                sreg[r] = (i == k) ? nrkj : hn;
            }
        }
    }
    if (j == kNS) {
        #pragma unroll
        for (int r = 0; r < kHalf; ++r) dnu_s[base + r] = sreg[r];
    }
    __syncthreads();

    // v_a = r1_a - dnu
    for (int m = tid; m < kNZ; m += 256) {
        int aa = m / kNS, ii = m - aa * kNS;
        vall[aa][ii] -= dnu_s[ii];
    }
    __syncthreads();

    // dz_a[j] = (Hinv_a v_a)_j via symmetry: sum over owned rows, 2-way combine
    if (act) {
        #pragma unroll
        for (int a = 0; a < kNW; ++a) {
            double p = 0.0;
            #pragma unroll
            for (int r = 0; r < kHalf; ++r)
                p += Hb[(size_t)a * kNS * kNS + (size_t)(base + r) * kNS + j]
                     * vall[a][base + r];
            tp2[a][h][j] = p;
        }
    }
    __syncthreads();
    for (int m = tid; m < kNZ; m += 256) {
        int aa = m / kNS, ii = m - aa * kNS;
        dzv[ii * kNW + aa] = tp2[aa][0][ii] + tp2[aa][1][ii];
    }
    __syncthreads();

    // step length
    double lmin = 1e300;
    double ds_l[4], dl_l[4];
    #pragma unroll
    for (int t = 0; t < 4; ++t) {
        int m = tid + t * 256;
        if (m < kNZ) {
            int ii = m / kNW, aa = m - ii * kNW;
            double yv = (labb[ii] == aa) ? 1.0 : 0.0;
            double zv = zb[m], sv = sb[m], lv = lb[m];
            double rp = zv + sv - 0.1 * yv;
            double rc = lv * sv - 0.1 * mu;
            double dz = dzv[m];
            double ds = -rp - dz;
            double dl = (-rc - lv * ds) / sv;
            ds_l[t] = ds; dl_l[t] = dl;
            if (ds < 0.0) lmin = fmin(lmin, -sv / ds);
            if (dl < 0.0) lmin = fmin(lmin, -lv / dl);
        }
    }
    red[tid] = lmin; __syncthreads();
    for (int off = 128; off > 0; off >>= 1) {
        if (tid < off) red[tid] = fmin(red[tid], red[tid + off]);
        __syncthreads();
    }
    const double alpha = fmin(1.0, 0.99 * red[0]);
    __syncthreads();

    // update + next mu
    double md = 0.0;
    #pragma unroll
    for (int t = 0; t < 4; ++t) {
        int m = tid + t * 256;
        if (m < kNZ) {
            double zn = zb[m] + alpha * dzv[m];
            double sn = sb[m] + alpha * ds_l[t];
            double ln = lb[m] + alpha * dl_l[t];
            zb[m] = zn; sb[m] = sn; lb[m] = ln;
            md += sn * ln;
        }
    }
    red[tid] = md; __syncthreads();
    for (int off = 128; off > 0; off >>= 1) {
        if (tid < off) red[tid] += red[tid + off];
        __syncthreads();
    }
    if (tid == 0) mu_g[b] = red[0] / kNZ;
    if (tid < kNS) nub[tid] += alpha * dnu_s[tid];
}

// -------------------------------------------------------------------------
// logits[b][q][n] = sum_s compat[b][s][q] * z[b][s*10+n]
__global__ __launch_bounds__(256) void logits_kernel(const float* __restrict__ compat,
                                                     const double* __restrict__ z,
                                                     float* __restrict__ out)
{
    const int b = blockIdx.x;
    const int tid = threadIdx.x;
    const float* cb = compat + (size_t)b * kNS * kNQ;
    const double* zb = z + (size_t)b * kNZ;
    __shared__ double zs[kNZ];
    for (int m = tid; m < kNZ; m += 256) zs[m] = zb[m];
    __syncthreads();
    for (int idx = tid; idx < kNQ * kNW; idx += 256) {
        int q = idx / kNW, n = idx - q * kNW;
        double acc = 0.0;
        for (int s2 = 0; s2 < kNS; ++s2)
            acc += (double)cb[(size_t)s2 * kNQ + q] * zs[s2 * kNW + n];
        out[(size_t)b * kNQ * kNW + idx] = (float)acc;
    }
}

// -------------------------------------------------------------------------
extern "C" void kernel_launch(void* const* d_in, const int* in_sizes, int n_in,
                              void* d_out, int out_size, void* d_ws, size_t ws_size,
                              hipStream_t stream)
{
    const float* sup    = (const float*)d_in[0];   // (32,10,10,512)
    const int*   labels = (const int*)  d_in[1];   // (32,10,10)
    const float* qry    = (const float*)d_in[2];   // (32,10,15,512)
    float* out = (float*)d_out;                    // (32,150,10) fp32

    char* ws = (char*)d_ws;
    size_t off = 0;
    auto alloc = [&](size_t bytes) -> void* {
        void* p = ws + off;
        off += (bytes + 255) & ~(size_t)255;
        return p;
    };
    double* K64    = (double*)alloc(sizeof(double) * kB * kNS * kNS);        // 2.56 MB
    double* z      = (double*)alloc(sizeof(double) * kB * kNZ);
    double* nu     = (double*)alloc(sizeof(double) * kB * kNS);
    double* s      = (double*)alloc(sizeof(double) * kB * kNZ);
    double* lam    = (double*)alloc(sizeof(double) * kB * kNZ);
    double* mu_g   = (double*)alloc(sizeof(double) * kB);
    double* Hinv   = (double*)alloc(sizeof(double) * kB * kNW * kNS * kNS);  // 25.6 MB
    double* tvec   = (double*)alloc(sizeof(double) * kB * kNW * kNS);
    double* r1g    = (double*)alloc(sizeof(double) * kB * kNW * kNS);
    float*  compat = (float*) alloc(sizeof(float)  * kB * kNS * kNQ);        // 1.92 MB

    gram_kernel  <<<dim3(kNS, kB), 128, 0, stream>>>(sup, K64);
    compat_kernel<<<dim3(kNS, kB), 256, 0, stream>>>(sup, qry, compat);
    init_kernel  <<<kB, 256, 0, stream>>>(z, nu, s, lam, mu_g);

    for (int it = 0; it < kIt; ++it) {
        ipm_invert_kernel<<<kB * kNW, 256, 0, stream>>>(K64, labels, z, nu, s, lam,
                                                        mu_g, Hinv, tvec, r1g);
        ipm_schur_kernel <<<kB, 256, 0, stream>>>(labels, Hinv, tvec, r1g,
                                                  z, nu, s, lam, mu_g);
    }

    logits_kernel<<<kB, 256, 0, stream>>>(compat, z, out);
}

// Round 3
// 16228.728 us; speedup vs baseline: 1.5544x; 1.5544x over previous
//
#include <hip/hip_runtime.h>

constexpr int kB   = 32;    // batch
constexpr int kNS  = 100;   // n_support
constexpr int kNW  = 10;    // n_way
constexpr int kNZ  = 1000;  // kNS*kNW
constexpr int kD   = 512;   // feature dim
constexpr int kNQ  = 150;   // N*Q query rows
constexpr int kIt  = 15;    // IPM iterations
constexpr int kHalf = 50;   // rows per register strip

// -------------------------------------------------------------------------
// K[b][i][j] = <sup_i, sup_j>  (fp32 accumulate, stored fp64 for the IPM)
__global__ __launch_bounds__(128) void gram_kernel(const float* __restrict__ sup,
                                                   double* __restrict__ K64)
{
    const int i = blockIdx.x;
    const int b = blockIdx.y;
    const int tid = threadIdx.x;
    __shared__ float rowi[kD];
    const float* supb = sup + (size_t)b * kNS * kD;
    reinterpret_cast<float4*>(rowi)[tid] =
        reinterpret_cast<const float4*>(supb + (size_t)i * kD)[tid];
    __syncthreads();
    for (int j = tid; j < kNS; j += 128) {
        const float4* rj = reinterpret_cast<const float4*>(supb + (size_t)j * kD);
        float acc = 0.0f;
        for (int d4 = 0; d4 < kD / 4; ++d4) {
            float4 v = rj[d4];
            acc += rowi[4*d4+0]*v.x + rowi[4*d4+1]*v.y
                 + rowi[4*d4+2]*v.z + rowi[4*d4+3]*v.w;
        }
        K64[((size_t)b * kNS + i) * kNS + j] = (double)acc;
    }
}

// compat[b][i][q] = <sup_i, qry_q>
__global__ __launch_bounds__(256) void compat_kernel(const float* __restrict__ sup,
                                                     const float* __restrict__ qry,
                                                     float* __restrict__ compat)
{
    const int i = blockIdx.x;
    const int b = blockIdx.y;
    const int tid = threadIdx.x;
    __shared__ float rowi[kD];
    const float* supb = sup + (size_t)b * kNS * kD;
    const float* qryb = qry + (size_t)b * kNQ * kD;
    if (tid < 128)
        reinterpret_cast<float4*>(rowi)[tid] =
            reinterpret_cast<const float4*>(supb + (size_t)i * kD)[tid];
    __syncthreads();
    for (int j = tid; j < kNQ; j += 256) {
        const float4* rj = reinterpret_cast<const float4*>(qryb + (size_t)j * kD);
        float acc = 0.0f;
        for (int d4 = 0; d4 < kD / 4; ++d4) {
            float4 v = rj[d4];
            acc += rowi[4*d4+0]*v.x + rowi[4*d4+1]*v.y
                 + rowi[4*d4+2]*v.z + rowi[4*d4+3]*v.w;
        }
        compat[((size_t)b * kNS + i) * kNQ + j] = acc;
    }
}

__global__ __launch_bounds__(256) void init_kernel(double* __restrict__ z,
                                                   double* __restrict__ nu,
                                                   double* __restrict__ s,
                                                   double* __restrict__ lam,
                                                   double* __restrict__ mu_g)
{
    const int b = blockIdx.x;
    const int tid = threadIdx.x;
    for (int m = tid; m < kNZ; m += 256) {
        z[b*kNZ + m]   = 0.0;
        s[b*kNZ + m]   = 1.0;
        lam[b*kNZ + m] = 1.0;
    }
    if (tid < kNS) nu[b*kNS + tid] = 0.0;
    if (tid == 0)  mu_g[b] = 1.0;   // dot(s0,lam0)/kNZ
}

// -------------------------------------------------------------------------
// One block per (b,a). Register-resident Gauss-Jordan inverse of
// H_a = K + diag(1 + lam_a/s_a). Thread (h=tid>>7, j=tid&127) owns rows
// [h*50, h*50+50) of column j. Pivot row k+1 is written AHEAD into
// rowk[(k+1)&1] during the (statically unrolled) update of pivot k, so the
// register strip is never dynamically indexed (no scratch spill).
__global__ __launch_bounds__(256) void ipm_invert_kernel(
    const double* __restrict__ K64, const int* __restrict__ labels,
    const double* __restrict__ z, const double* __restrict__ nu,
    const double* __restrict__ s, const double* __restrict__ lam,
    const double* __restrict__ mu_g,
    double* __restrict__ Hinv, double* __restrict__ tvec,
    double* __restrict__ r1g)
{
    const int b = blockIdx.x / kNW;
    const int a = blockIdx.x - b * kNW;
    const int tid = threadIdx.x;
    const int h = tid >> 7;
    const int j = tid & 127;
    const bool act = (j < kNS);
    const int base = h * kHalf;

    __shared__ double za[kNS], sa[kNS], la[kNS], da[kNS], nus[kNS], r1s[kNS];
    __shared__ double part2[2][kNS];
    __shared__ double rowk[2][kNS + 4];
    __shared__ int    labs[kNS];

    const double* zb = z   + (size_t)b * kNZ;
    const double* sb = s   + (size_t)b * kNZ;
    const double* lb = lam + (size_t)b * kNZ;
    const double* Kb = K64 + (size_t)b * kNS * kNS;

    if (tid < kNS) {
        double zv = zb[tid * kNW + a];
        double sv = sb[tid * kNW + a];
        double lv = lb[tid * kNW + a];
        za[tid] = zv; sa[tid] = sv; la[tid] = lv; da[tid] = lv / sv;
        nus[tid]  = nu[b * kNS + tid];
        labs[tid] = labels[b * kNS + tid];
    }
    __syncthreads();

    // Build H column j in registers; fused partial of (K z_a) via symmetry.
    double hreg[kHalf];
    if (act) {
        double kzp = 0.0;
        #pragma unroll
        for (int r = 0; r < kHalf; ++r) {
            const int i = base + r;
            double kv = Kb[(size_t)i * kNS + j];
            kzp += kv * za[i];
            hreg[r] = (i == j) ? (kv + 1.0 + da[j]) : kv;
        }
        part2[h][j] = kzp;
        if (h == 0) rowk[0][j] = hreg[0];      // seed pivot row 0 (static idx)
    }
    __syncthreads();
    if (tid < kNS) {
        const double mu = mu_g[b];
        const int i = tid;
        double kz = part2[0][i] + part2[1][i];
        double yv = (labs[i] == a) ? 1.0 : 0.0;
        double rd = kz + za[i] - yv + la[i] + nus[i];
        double rp = za[i] + sa[i] - 0.1 * yv;      // h = C_REG*y
        double rc = la[i] * sa[i] - 0.1 * mu;      // sigma = 0.1
        double v = -rd + (rc - la[i] * rp) / sa[i];
        r1s[i] = v;
        r1g[(size_t)(b * kNW + a) * kNS + i] = v;
    }

    // Gauss-Jordan in-place inverse, 1 barrier per pivot.
    #pragma unroll 1
    for (int k = 0; k < kNS; ++k) {
        const int buf = k & 1;
        __syncthreads();                       // rowk[buf] now complete
        if (act) {
            const double pivinv = 1.0 / rowk[buf][k];
            const bool jk = (j == k);
            const double nrkj = (jk ? 1.0 : rowk[buf][j]) * pivinv;
            #pragma unroll
            for (int r = 0; r < kHalf; ++r) {
                const int i = base + r;
                double rv = rowk[buf][i];           // broadcast read
                double ci = (i < k) ? -rv : rv;     // symmetric-GJ invariant
                double he = jk ? 0.0 : hreg[r];
                double hn = he - ci * nrkj;
                hreg[r] = (i == k) ? nrkj : hn;
                if (i == k + 1) rowk[1 - buf][j] = hn;   // write-ahead pivot row
            }
        }
    }

    // Write Hinv (coalesced) + t_a = Hinv * r1 (2-way combine via symmetry)
    double* Hb = Hinv + (size_t)(b * kNW + a) * kNS * kNS;
    if (act) {
        double tp = 0.0;
        #pragma unroll
        for (int r = 0; r < kHalf; ++r) {
            Hb[(size_t)(base + r) * kNS + j] = hreg[r];
            tp += hreg[r] * r1s[base + r];
        }
        part2[h][j] = tp;
    }
    __syncthreads();
    if (tid < kNS)
        tvec[(size_t)(b * kNW + a) * kNS + tid] = part2[0][tid] + part2[1][tid];
}

// -------------------------------------------------------------------------
// One block per b: S = sum_a Hinv_a (registers), GJ solve [S | rhs],
// dz_a = Hinv_a (r1_a - dnu) via coalesced streaming + symmetry,
// min-ratio step, state update, next-iteration mu.
__global__ __launch_bounds__(256) void ipm_schur_kernel(
    const int* __restrict__ labels,
    const double* __restrict__ Hinv, const double* __restrict__ tvec,
    const double* __restrict__ r1g,
    double* __restrict__ z, double* __restrict__ nu,
    double* __restrict__ s, double* __restrict__ lam,
    double* __restrict__ mu_g)
{
    const int b = blockIdx.x;
    const int tid = threadIdx.x;
    const int h = tid >> 7;
    const int j = tid & 127;
    const int base = h * kHalf;
    const bool act  = (j < kNS);     // matrix columns
    const bool actS = (j <= kNS);    // + rhs column (j == 100)

    __shared__ double vall[kNW][kNS];     // r1_a, then v_a = r1_a - dnu
    __shared__ double rhs[kNS];
    __shared__ double dnu_s[kNS];
    __shared__ double rowk[2][kNS + 8];
    __shared__ double tp2[kNW][2][kNS];
    __shared__ double dzv[kNZ];
    __shared__ double red[256];

    double* zb  = z   + (size_t)b * kNZ;
    double* sb  = s   + (size_t)b * kNZ;
    double* lb  = lam + (size_t)b * kNZ;
    double* nub = nu  + (size_t)b * kNS;
    const double* Hb  = Hinv + (size_t)b * kNW * kNS * kNS;
    const double* tb  = tvec + (size_t)b * kNW * kNS;
    const double* r1b = r1g  + (size_t)b * kNW * kNS;
    const int* labb = labels + b * kNS;
    const double mu = mu_g[b];

    for (int m = tid; m < kNZ; m += 256) {
        int aa = m / kNS, ii = m - aa * kNS;
        vall[aa][ii] = r1b[m];
    }
    if (tid < kNS) {
        double acc = 0.0, rp2 = 0.0;
        #pragma unroll
        for (int a = 0; a < kNW; ++a) {
            acc += tb[a * kNS + tid];
            rp2 += zb[tid * kNW + a];
        }
        rhs[tid] = acc + rp2;
    }
    __syncthreads();

    // S columns in registers (coalesced streaming read of Hinv);
    // rhs column lives in the j==kNS threads.
    double sreg[kHalf];
    if (act) {
        #pragma unroll
        for (int r = 0; r < kHalf; ++r) {
            double acc = 0.0;
            #pragma unroll
            for (int a = 0; a < kNW; ++a)
                acc += Hb[(size_t)a * kNS * kNS + (size_t)(base + r) * kNS + j];
            sreg[r] = acc;
        }
    } else if (j == kNS) {
        #pragma unroll
        for (int r = 0; r < kHalf; ++r) sreg[r] = rhs[base + r];
    }
    if (actS && h == 0) rowk[0][j] = sreg[0];     // seed pivot row 0

    // GJ (inverse-style recurrence, write-ahead pivot row); the rhs column
    // (j==100, never ==k) receives pure row ops -> solution.
    #pragma unroll 1
    for (int k = 0; k < kNS; ++k) {
        const int buf = k & 1;
        __syncthreads();
        if (actS) {
            const double pivinv = 1.0 / rowk[buf][k];
            const bool jk = (j == k);
            const double nrkj = (jk ? 1.0 : rowk[buf][j]) * pivinv;
            #pragma unroll
            for (int r = 0; r < kHalf; ++r) {
                const int i = base + r;
                double rv = rowk[buf][i];
                double ci = (i < k) ? -rv : rv;
                double he = jk ? 0.0 : sreg[r];
                double hn = he - ci * nrkj;
                sreg[r] = (i == k) ? nrkj : hn;
                if (i == k + 1) rowk[1 - buf][j] = hn;
            }
        }
    }
    if (j == kNS) {
        #pragma unroll
        for (int r = 0; r < kHalf; ++r) dnu_s[base + r] = sreg[r];
    }
    __syncthreads();

    // v_a = r1_a - dnu
    for (int m = tid; m < kNZ; m += 256) {
        int aa = m / kNS, ii = m - aa * kNS;
        vall[aa][ii] -= dnu_s[ii];
    }
    __syncthreads();

    // dz_a[j] = (Hinv_a v_a)_j via symmetry: sum over owned rows, 2-way combine
    if (act) {
        #pragma unroll
        for (int a = 0; a < kNW; ++a) {
            double p = 0.0;
            #pragma unroll
            for (int r = 0; r < kHalf; ++r)
                p += Hb[(size_t)a * kNS * kNS + (size_t)(base + r) * kNS + j]
                     * vall[a][base + r];
            tp2[a][h][j] = p;
        }
    }
    __syncthreads();
    for (int m = tid; m < kNZ; m += 256) {
        int aa = m / kNS, ii = m - aa * kNS;
        dzv[ii * kNW + aa] = tp2[aa][0][ii] + tp2[aa][1][ii];
    }
    __syncthreads();

    // step length
    double lmin = 1e300;
    double ds_l[4], dl_l[4];
    #pragma unroll
    for (int t = 0; t < 4; ++t) {
        int m = tid + t * 256;
        if (m < kNZ) {
            int ii = m / kNW, aa = m - ii * kNW;
            double yv = (labb[ii] == aa) ? 1.0 : 0.0;
            double zv = zb[m], sv = sb[m], lv = lb[m];
            double rp = zv + sv - 0.1 * yv;
            double rc = lv * sv - 0.1 * mu;
            double dz = dzv[m];
            double ds = -rp - dz;
            double dl = (-rc - lv * ds) / sv;
            ds_l[t] = ds; dl_l[t] = dl;
            if (ds < 0.0) lmin = fmin(lmin, -sv / ds);
            if (dl < 0.0) lmin = fmin(lmin, -lv / dl);
        }
    }
    red[tid] = lmin; __syncthreads();
    for (int off = 128; off > 0; off >>= 1) {
        if (tid < off) red[tid] = fmin(red[tid], red[tid + off]);
        __syncthreads();
    }
    const double alpha = fmin(1.0, 0.99 * red[0]);
    __syncthreads();

    // update + next mu
    double md = 0.0;
    #pragma unroll
    for (int t = 0; t < 4; ++t) {
        int m = tid + t * 256;
        if (m < kNZ) {
            double zn = zb[m] + alpha * dzv[m];
            double sn = sb[m] + alpha * ds_l[t];
            double ln = lb[m] + alpha * dl_l[t];
            zb[m] = zn; sb[m] = sn; lb[m] = ln;
            md += sn * ln;
        }
    }
    red[tid] = md; __syncthreads();
    for (int off = 128; off > 0; off >>= 1) {
        if (tid < off) red[tid] += red[tid + off];
        __syncthreads();
    }
    if (tid == 0) mu_g[b] = red[0] / kNZ;
    if (tid < kNS) nub[tid] += alpha * dnu_s[tid];
}

// -------------------------------------------------------------------------
// logits[b][q][n] = sum_s compat[b][s][q] * z[b][s*10+n]
__global__ __launch_bounds__(256) void logits_kernel(const float* __restrict__ compat,
                                                     const double* __restrict__ z,
                                                     float* __restrict__ out)
{
    const int b = blockIdx.x;
    const int tid = threadIdx.x;
    const float* cb = compat + (size_t)b * kNS * kNQ;
    const double* zb = z + (size_t)b * kNZ;
    __shared__ double zs[kNZ];
    for (int m = tid; m < kNZ; m += 256) zs[m] = zb[m];
    __syncthreads();
    for (int idx = tid; idx < kNQ * kNW; idx += 256) {
        int q = idx / kNW, n = idx - q * kNW;
        double acc = 0.0;
        for (int s2 = 0; s2 < kNS; ++s2)
            acc += (double)cb[(size_t)s2 * kNQ + q] * zs[s2 * kNW + n];
        out[(size_t)b * kNQ * kNW + idx] = (float)acc;
    }
}

// -------------------------------------------------------------------------
extern "C" void kernel_launch(void* const* d_in, const int* in_sizes, int n_in,
                              void* d_out, int out_size, void* d_ws, size_t ws_size,
                              hipStream_t stream)
{
    const float* sup    = (const float*)d_in[0];   // (32,10,10,512)
    const int*   labels = (const int*)  d_in[1];   // (32,10,10)
    const float* qry    = (const float*)d_in[2];   // (32,10,15,512)
    float* out = (float*)d_out;                    // (32,150,10) fp32

    char* ws = (char*)d_ws;
    size_t off = 0;
    auto alloc = [&](size_t bytes) -> void* {
        void* p = ws + off;
        off += (bytes + 255) & ~(size_t)255;
        return p;
    };
    double* K64    = (double*)alloc(sizeof(double) * kB * kNS * kNS);        // 2.56 MB
    double* z      = (double*)alloc(sizeof(double) * kB * kNZ);
    double* nu     = (double*)alloc(sizeof(double) * kB * kNS);
    double* s      = (double*)alloc(sizeof(double) * kB * kNZ);
    double* lam    = (double*)alloc(sizeof(double) * kB * kNZ);
    double* mu_g   = (double*)alloc(sizeof(double) * kB);
    double* Hinv   = (double*)alloc(sizeof(double) * kB * kNW * kNS * kNS);  // 25.6 MB
    double* tvec   = (double*)alloc(sizeof(double) * kB * kNW * kNS);
    double* r1g    = (double*)alloc(sizeof(double) * kB * kNW * kNS);
    float*  compat = (float*) alloc(sizeof(float)  * kB * kNS * kNQ);        // 1.92 MB

    gram_kernel  <<<dim3(kNS, kB), 128, 0, stream>>>(sup, K64);
    compat_kernel<<<dim3(kNS, kB), 256, 0, stream>>>(sup, qry, compat);
    init_kernel  <<<kB, 256, 0, stream>>>(z, nu, s, lam, mu_g);

    for (int it = 0; it < kIt; ++it) {
        ipm_invert_kernel<<<kB * kNW, 256, 0, stream>>>(K64, labels, z, nu, s, lam,
                                                        mu_g, Hinv, tvec, r1g);
        ipm_schur_kernel <<<kB, 256, 0, stream>>>(labels, Hinv, tvec, r1g,
                                                  z, nu, s, lam, mu_g);
    }

    logits_kernel<<<kB, 256, 0, stream>>>(compat, z, out);
}

// Round 4
// 7227.048 us; speedup vs baseline: 3.4904x; 2.2456x over previous
//
#include <hip/hip_runtime.h>

constexpr int kB   = 32;    // batch
constexpr int kNS  = 100;   // n_support
constexpr int kNW  = 10;    // n_way
constexpr int kNZ  = 1000;  // kNS*kNW
constexpr int kD   = 512;   // feature dim
constexpr int kNQ  = 150;   // N*Q query rows
constexpr int kIt  = 15;    // IPM iterations
constexpr int kHalf = 50;   // rows per register strip (invert)
constexpr int kQrt  = 25;   // rows per register strip (schur)

// -------------------------------------------------------------------------
// K[b][i][j] = <sup_i, sup_j>  (fp32 accumulate, stored fp64 for the IPM)
__global__ __launch_bounds__(128) void gram_kernel(const float* __restrict__ sup,
                                                   double* __restrict__ K64)
{
    const int i = blockIdx.x;
    const int b = blockIdx.y;
    const int tid = threadIdx.x;
    __shared__ float rowi[kD];
    const float* supb = sup + (size_t)b * kNS * kD;
    reinterpret_cast<float4*>(rowi)[tid] =
        reinterpret_cast<const float4*>(supb + (size_t)i * kD)[tid];
    __syncthreads();
    for (int j = tid; j < kNS; j += 128) {
        const float4* rj = reinterpret_cast<const float4*>(supb + (size_t)j * kD);
        float acc = 0.0f;
        for (int d4 = 0; d4 < kD / 4; ++d4) {
            float4 v = rj[d4];
            acc += rowi[4*d4+0]*v.x + rowi[4*d4+1]*v.y
                 + rowi[4*d4+2]*v.z + rowi[4*d4+3]*v.w;
        }
        K64[((size_t)b * kNS + i) * kNS + j] = (double)acc;
    }
}

// compat[b][i][q] = <sup_i, qry_q>
__global__ __launch_bounds__(256) void compat_kernel(const float* __restrict__ sup,
                                                     const float* __restrict__ qry,
                                                     float* __restrict__ compat)
{
    const int i = blockIdx.x;
    const int b = blockIdx.y;
    const int tid = threadIdx.x;
    __shared__ float rowi[kD];
    const float* supb = sup + (size_t)b * kNS * kD;
    const float* qryb = qry + (size_t)b * kNQ * kD;
    if (tid < 128)
        reinterpret_cast<float4*>(rowi)[tid] =
            reinterpret_cast<const float4*>(supb + (size_t)i * kD)[tid];
    __syncthreads();
    for (int j = tid; j < kNQ; j += 256) {
        const float4* rj = reinterpret_cast<const float4*>(qryb + (size_t)j * kD);
        float acc = 0.0f;
        for (int d4 = 0; d4 < kD / 4; ++d4) {
            float4 v = rj[d4];
            acc += rowi[4*d4+0]*v.x + rowi[4*d4+1]*v.y
                 + rowi[4*d4+2]*v.z + rowi[4*d4+3]*v.w;
        }
        compat[((size_t)b * kNS + i) * kNQ + j] = acc;
    }
}

__global__ __launch_bounds__(256) void init_kernel(double* __restrict__ z,
                                                   double* __restrict__ nu,
                                                   double* __restrict__ s,
                                                   double* __restrict__ lam,
                                                   double* __restrict__ mu_g)
{
    const int b = blockIdx.x;
    const int tid = threadIdx.x;
    for (int m = tid; m < kNZ; m += 256) {
        z[b*kNZ + m]   = 0.0;
        s[b*kNZ + m]   = 1.0;
        lam[b*kNZ + m] = 1.0;
    }
    if (tid < kNS) nu[b*kNS + tid] = 0.0;
    if (tid == 0)  mu_g[b] = 1.0;   // dot(s0,lam0)/kNZ
}

// -------------------------------------------------------------------------
// 512 threads = 2 classes; each 256-thread half: (h=t>>7, j=t&127) owns rows
// [h*50,h*50+50) of column j of H_a = K + diag(1 + lam_a/s_a).
// Signed pivot-row storage: rowk[i] = sigma_i*H[k][i] (sigma=-1 for i<k), so
// the multiplier H[i][k] == rowk[i] raw (symmetric-GJ invariant) — no per-row
// select. Pivot reciprocal is computed write-ahead by the next diagonal owner.
__global__ __launch_bounds__(512, 2) void ipm_invert_kernel(
    const double* __restrict__ K64, const int* __restrict__ labels,
    const double* __restrict__ z, const double* __restrict__ nu,
    const double* __restrict__ s, const double* __restrict__ lam,
    const double* __restrict__ mu_g,
    double* __restrict__ Hinv, double* __restrict__ tvec)
{
    const int bid = blockIdx.x;          // [0, 160)
    const int b = bid / 5;
    const int pair = bid - b * 5;
    const int tid = threadIdx.x;
    const int sub = tid >> 8;            // class within pair
    const int a = pair * 2 + sub;
    const int t = tid & 255;
    const int h = t >> 7;
    const int j = t & 127;
    const bool act = (j < kNS);
    const int base = h * kHalf;

    __shared__ double za[2][kNS], sa[2][kNS], la[2][kNS], da[2][kNS];
    __shared__ double nus[kNS], r1s[2][kNS];
    __shared__ double part2[2][2][kNS];
    __shared__ double rowk[2][2][kNS + 8];   // [sub][buf][0..99]=row, [100]=pivinv
    __shared__ int    labs[kNS];

    const double* zb = z   + (size_t)b * kNZ;
    const double* sb = s   + (size_t)b * kNZ;
    const double* lb = lam + (size_t)b * kNZ;
    const double* Kb = K64 + (size_t)b * kNS * kNS;

    if (t < kNS) {
        double zv = zb[t * kNW + a];
        double sv = sb[t * kNW + a];
        double lv = lb[t * kNW + a];
        za[sub][t] = zv; sa[sub][t] = sv; la[sub][t] = lv; da[sub][t] = lv / sv;
    }
    if (tid < kNS) {
        nus[tid]  = nu[b * kNS + tid];
        labs[tid] = labels[b * kNS + tid];
    }
    __syncthreads();

    // Build H column j in registers; fused partial of (K z_a) via symmetry.
    double hreg[kHalf];
    if (act) {
        double kzp = 0.0;
        #pragma unroll
        for (int r = 0; r < kHalf; ++r) {
            const int i = base + r;
            double kv = Kb[(size_t)i * kNS + j];
            kzp += kv * za[sub][i];
            hreg[r] = (i == j) ? (kv + 1.0 + da[sub][j]) : kv;
        }
        part2[sub][h][j] = kzp;
        if (h == 0) {
            rowk[sub][0][j] = hreg[0];                       // seed pivot row 0
            if (j == 0) rowk[sub][0][kNS] = 1.0 / hreg[0];   // seed pivinv
        }
    }
    __syncthreads();
    if (t < kNS) {
        const double mu = mu_g[b];
        const int i = t;
        double kz = part2[sub][0][i] + part2[sub][1][i];
        double yv = (labs[i] == a) ? 1.0 : 0.0;
        double rd = kz + za[sub][i] - yv + la[sub][i] + nus[i];
        double rp = za[sub][i] + sa[sub][i] - 0.1 * yv;   // h = C_REG*y
        double rc = la[sub][i] * sa[sub][i] - 0.1 * mu;   // sigma = 0.1
        r1s[sub][i] = -rd + (rc - la[sub][i] * rp) / sa[sub][i];
    }

    // Gauss-Jordan in-place inverse, 1 barrier per pivot.
    #pragma unroll 1
    for (int k = 0; k < kNS; ++k) {
        const int buf = k & 1, nb = 1 - buf;
        __syncthreads();                     // rowk[sub][buf] complete
        if (act) {
            const double P  = rowk[sub][buf][kNS];
            const double Sj = rowk[sub][buf][j];
            const bool jk = (j == k);
            const double sigj  = (j < k) ? -1.0 : 1.0;
            const double nrkj  = jk ? P : sigj * Sj * P;
            const double jkmul = jk ? 0.0 : 1.0;
            #pragma unroll
            for (int c = 0; c < 2; ++c) {
                double rk[kQrt];
                #pragma unroll
                for (int u = 0; u < kQrt; ++u)
                    rk[u] = rowk[sub][buf][base + c * kQrt + u];
                #pragma unroll
                for (int u = 0; u < kQrt; ++u) {
                    const int i = base + c * kQrt + u;
                    const int r = c * kQrt + u;
                    double he = jkmul * hreg[r];
                    double hn = fma(-rk[u], nrkj, he);
                    hreg[r] = (i == k) ? nrkj : hn;
                    if (i == k + 1) {
                        rowk[sub][nb][j] = (j <= k) ? -hn : hn;   // signed store
                        if (j == k + 1) rowk[sub][nb][kNS] = 1.0 / hn;
                    }
                }
            }
        }
    }

    // Write Hinv (coalesced) + t_a = Hinv * r1 (2-way combine via symmetry)
    double* Hb = Hinv + (size_t)(b * kNW + a) * kNS * kNS;
    if (act) {
        double tp = 0.0;
        #pragma unroll
        for (int r = 0; r < kHalf; ++r) {
            Hb[(size_t)(base + r) * kNS + j] = hreg[r];
            tp += hreg[r] * r1s[sub][base + r];
        }
        part2[sub][h][j] = tp;
    }
    __syncthreads();
    if (t < kNS)
        tvec[(size_t)(b * kNW + a) * kNS + t] = part2[sub][0][t] + part2[sub][1][t];
}

// -------------------------------------------------------------------------
// One block per b, 512 threads: quarter-strips (q=tid>>7 owns 25 rows of
// column j=tid&127; j==100 is the RHS column). S = sum_a Hinv_a, GJ-solve
// S dnu = sum_a t_a + rp2 with the same signed-row/pivinv-write-ahead tricks.
__global__ __launch_bounds__(512, 2) void schur_solve_kernel(
    const double* __restrict__ Hinv, const double* __restrict__ tvec,
    const double* __restrict__ z, double* __restrict__ dnu_g)
{
    const int b = blockIdx.x;
    const int tid = threadIdx.x;
    const int q = tid >> 7;
    const int j = tid & 127;
    const int base = q * kQrt;
    const bool act  = (j < kNS);
    const bool actS = (j <= kNS);

    __shared__ double rhs[kNS];
    __shared__ double rowk[2][kNS + 8];   // [0..99]=row, [100]=rhs col, [101]=pivinv

    const double* Hb = Hinv + (size_t)b * kNW * kNS * kNS;
    const double* tb = tvec + (size_t)b * kNW * kNS;
    const double* zb = z    + (size_t)b * kNZ;

    if (tid < kNS) {
        double acc = 0.0, rp2 = 0.0;
        #pragma unroll
        for (int a = 0; a < kNW; ++a) {
            acc += tb[a * kNS + tid];
            rp2 += zb[tid * kNW + a];
        }
        rhs[tid] = acc + rp2;
    }
    __syncthreads();

    // S columns (or rhs column) in registers
    double sreg[kQrt];
    if (act) {
        #pragma unroll
        for (int u = 0; u < kQrt; ++u) {
            double acc = 0.0;
            #pragma unroll
            for (int a = 0; a < kNW; ++a)
                acc += Hb[(size_t)a * kNS * kNS + (size_t)(base + u) * kNS + j];
            sreg[u] = acc;
        }
    } else if (j == kNS) {
        #pragma unroll
        for (int u = 0; u < kQrt; ++u) sreg[u] = rhs[base + u];
    }
    if (actS && q == 0) {
        rowk[0][j] = sreg[0];
        if (j == 0) rowk[0][kNS + 1] = 1.0 / sreg[0];
    }

    #pragma unroll 1
    for (int k = 0; k < kNS; ++k) {
        const int buf = k & 1, nb = 1 - buf;
        __syncthreads();
        if (actS) {
            const double P  = rowk[buf][kNS + 1];
            const double Sj = rowk[buf][j];
            const bool jk = (j == k);
            const double sigj  = (j < k) ? -1.0 : 1.0;
            const double nrkj  = jk ? P : sigj * Sj * P;
            const double jkmul = jk ? 0.0 : 1.0;
            double rk[kQrt];
            #pragma unroll
            for (int u = 0; u < kQrt; ++u)
                rk[u] = rowk[buf][base + u];
            #pragma unroll
            for (int u = 0; u < kQrt; ++u) {
                const int i = base + u;
                double he = jkmul * sreg[u];
                double hn = fma(-rk[u], nrkj, he);
                sreg[u] = (i == k) ? nrkj : hn;
                if (i == k + 1) {
                    rowk[nb][j] = (j <= k) ? -hn : hn;
                    if (j == k + 1) rowk[nb][kNS + 1] = 1.0 / hn;
                }
            }
        }
    }

    if (j == kNS) {
        #pragma unroll
        for (int u = 0; u < kQrt; ++u)
            dnu_g[(size_t)b * kNS + base + u] = sreg[u];
    }
}

// -------------------------------------------------------------------------
// One block per (b,a): dz_a = t_a - Hinv_a*dnu (full-GPU streaming of Hinv),
// ds/dlam, per-block min step-ratio.
__global__ __launch_bounds__(256) void dz_kernel(
    const int* __restrict__ labels,
    const double* __restrict__ Hinv, const double* __restrict__ tvec,
    const double* __restrict__ dnu_g,
    const double* __restrict__ z, const double* __restrict__ s,
    const double* __restrict__ lam, const double* __restrict__ mu_g,
    double* __restrict__ dz_g, double* __restrict__ ds_g,
    double* __restrict__ dl_g, double* __restrict__ minr_g)
{
    const int b = blockIdx.x / kNW;
    const int a = blockIdx.x - b * kNW;
    const int tid = threadIdx.x;
    const int h = tid >> 7;
    const int j = tid & 127;

    __shared__ double dnus[kNS];
    __shared__ double p2[2][kNS];
    __shared__ double red[256];

    const double* Hb = Hinv + (size_t)(b * kNW + a) * kNS * kNS;

    if (tid < kNS) dnus[tid] = dnu_g[(size_t)b * kNS + tid];
    __syncthreads();

    if (j < kNS) {
        double p = 0.0;
        #pragma unroll
        for (int r = 0; r < kHalf; ++r)
            p += Hb[(size_t)(h * kHalf + r) * kNS + j] * dnus[h * kHalf + r];
        p2[h][j] = p;
    }
    __syncthreads();

    double lmin = 1e300;
    if (tid < kNS) {
        const int i = tid;
        const size_t m = (size_t)b * kNZ + i * kNW + a;
        const double mu = mu_g[b];
        double dz = tvec[(size_t)(b * kNW + a) * kNS + i] - (p2[0][i] + p2[1][i]);
        double yv = (labels[b * kNS + i] == a) ? 1.0 : 0.0;
        double zv = z[m], sv = s[m], lv = lam[m];
        double rp = zv + sv - 0.1 * yv;
        double rc = lv * sv - 0.1 * mu;
        double ds = -rp - dz;
        double dl = (-rc - lv * ds) / sv;
        dz_g[m] = dz; ds_g[m] = ds; dl_g[m] = dl;
        if (ds < 0.0) lmin = fmin(lmin, -sv / ds);
        if (dl < 0.0) lmin = fmin(lmin, -lv / dl);
    }
    red[tid] = lmin; __syncthreads();
    for (int off = 128; off > 0; off >>= 1) {
        if (tid < off) red[tid] = fmin(red[tid], red[tid + off]);
        __syncthreads();
    }
    if (tid == 0) minr_g[b * kNW + a] = red[0];
}

// -------------------------------------------------------------------------
// One block per b: alpha from the 10 per-class mins, state update, next mu.
__global__ __launch_bounds__(256) void update_kernel(
    const double* __restrict__ minr_g, const double* __restrict__ dnu_g,
    const double* __restrict__ dz_g, const double* __restrict__ ds_g,
    const double* __restrict__ dl_g,
    double* __restrict__ z, double* __restrict__ nu,
    double* __restrict__ s, double* __restrict__ lam,
    double* __restrict__ mu_g)
{
    const int b = blockIdx.x;
    const int tid = threadIdx.x;
    __shared__ double red[256];

    double am = 1e300;
    #pragma unroll
    for (int a = 0; a < kNW; ++a) am = fmin(am, minr_g[b * kNW + a]);
    const double alpha = fmin(1.0, 0.99 * am);

    double* zb = z   + (size_t)b * kNZ;
    double* sb = s   + (size_t)b * kNZ;
    double* lb = lam + (size_t)b * kNZ;

    double md = 0.0;
    #pragma unroll
    for (int tcl = 0; tcl < 4; ++tcl) {
        const size_t m = (size_t)b * kNZ + tid + tcl * 256;
        if (tid + tcl * 256 < kNZ) {
            double zn = zb[tid + tcl*256] + alpha * dz_g[m];
            double sn = sb[tid + tcl*256] + alpha * ds_g[m];
            double ln = lb[tid + tcl*256] + alpha * dl_g[m];
            zb[tid + tcl*256] = zn; sb[tid + tcl*256] = sn; lb[tid + tcl*256] = ln;
            md += sn * ln;
        }
    }
    red[tid] = md; __syncthreads();
    for (int off = 128; off > 0; off >>= 1) {
        if (tid < off) red[tid] += red[tid + off];
        __syncthreads();
    }
    if (tid == 0) mu_g[b] = red[0] / kNZ;
    if (tid < kNS) nu[(size_t)b * kNS + tid] += alpha * dnu_g[(size_t)b * kNS + tid];
}

// -------------------------------------------------------------------------
// logits[b][q][n] = sum_s compat[b][s][q] * z[b][s*10+n]
__global__ __launch_bounds__(256) void logits_kernel(const float* __restrict__ compat,
                                                     const double* __restrict__ z,
                                                     float* __restrict__ out)
{
    const int b = blockIdx.x;
    const int tid = threadIdx.x;
    const float* cb = compat + (size_t)b * kNS * kNQ;
    const double* zb = z + (size_t)b * kNZ;
    __shared__ double zs[kNZ];
    for (int m = tid; m < kNZ; m += 256) zs[m] = zb[m];
    __syncthreads();
    for (int idx = tid; idx < kNQ * kNW; idx += 256) {
        int q = idx / kNW, n = idx - q * kNW;
        double acc = 0.0;
        for (int s2 = 0; s2 < kNS; ++s2)
            acc += (double)cb[(size_t)s2 * kNQ + q] * zs[s2 * kNW + n];
        out[(size_t)b * kNQ * kNW + idx] = (float)acc;
    }
}

// -------------------------------------------------------------------------
extern "C" void kernel_launch(void* const* d_in, const int* in_sizes, int n_in,
                              void* d_out, int out_size, void* d_ws, size_t ws_size,
                              hipStream_t stream)
{
    const float* sup    = (const float*)d_in[0];   // (32,10,10,512)
    const int*   labels = (const int*)  d_in[1];   // (32,10,10)
    const float* qry    = (const float*)d_in[2];   // (32,10,15,512)
    float* out = (float*)d_out;                    // (32,150,10) fp32

    char* ws = (char*)d_ws;
    size_t off = 0;
    auto alloc = [&](size_t bytes) -> void* {
        void* p = ws + off;
        off += (bytes + 255) & ~(size_t)255;
        return p;
    };
    double* K64    = (double*)alloc(sizeof(double) * kB * kNS * kNS);        // 2.56 MB
    double* z      = (double*)alloc(sizeof(double) * kB * kNZ);
    double* nu     = (double*)alloc(sizeof(double) * kB * kNS);
    double* s      = (double*)alloc(sizeof(double) * kB * kNZ);
    double* lam    = (double*)alloc(sizeof(double) * kB * kNZ);
    double* mu_g   = (double*)alloc(sizeof(double) * kB);
    double* Hinv   = (double*)alloc(sizeof(double) * kB * kNW * kNS * kNS);  // 25.6 MB
    double* tvec   = (double*)alloc(sizeof(double) * kB * kNW * kNS);
    double* dnu_g  = (double*)alloc(sizeof(double) * kB * kNS);
    double* dz_g   = (double*)alloc(sizeof(double) * kB * kNZ);
    double* ds_g   = (double*)alloc(sizeof(double) * kB * kNZ);
    double* dl_g   = (double*)alloc(sizeof(double) * kB * kNZ);
    double* minr_g = (double*)alloc(sizeof(double) * kB * kNW);
    float*  compat = (float*) alloc(sizeof(float)  * kB * kNS * kNQ);        // 1.92 MB

    gram_kernel  <<<dim3(kNS, kB), 128, 0, stream>>>(sup, K64);
    compat_kernel<<<dim3(kNS, kB), 256, 0, stream>>>(sup, qry, compat);
    init_kernel  <<<kB, 256, 0, stream>>>(z, nu, s, lam, mu_g);

    for (int it = 0; it < kIt; ++it) {
        ipm_invert_kernel<<<kB * kNW / 2, 512, 0, stream>>>(K64, labels, z, nu, s,
                                                            lam, mu_g, Hinv, tvec);
        schur_solve_kernel<<<kB, 512, 0, stream>>>(Hinv, tvec, z, dnu_g);
        dz_kernel<<<kB * kNW, 256, 0, stream>>>(labels, Hinv, tvec, dnu_g,
                                                z, s, lam, mu_g,
                                                dz_g, ds_g, dl_g, minr_g);
        update_kernel<<<kB, 256, 0, stream>>>(minr_g, dnu_g, dz_g, ds_g, dl_g,
                                              z, nu, s, lam, mu_g);
    }

    logits_kernel<<<kB, 256, 0, stream>>>(compat, z, out);
}